// Round 10
// baseline (2817.124 us; speedup 1.0000x reference)
//
#include <hip/hip_runtime.h>
#include <math.h>

#define BB 256
#define TT 512
#define DD 256
#define HH 512
#define SS 8
#define G4H 2048
#define BH (BB*HH)          // 131072
#define OUT_BASE ((size_t)BB*TT*DD)
#define XSLOT_U32 8192      // 32 KB per group-slot: 32 rows x 256 u32 (fp16 pairs)

typedef _Float16 f16;
typedef __attribute__((ext_vector_type(8)))  _Float16 f16x8;
typedef __attribute__((ext_vector_type(16))) float    f32x16;

__device__ __forceinline__ float sigm(float x) { return 1.f / (1.f + __expf(-x)); }
__device__ __forceinline__ float ftanh(float x) {
  x = fminf(15.f, fmaxf(-15.f, x));
  float e = __expf(-2.f * x);
  return (1.f - e) / (1.f + e);
}

// ---- dual-path sync primitives: fast = XCD-local L2 (sc0), slow = L3 (sc1) ----
__device__ __forceinline__ int flag_load(const int* p, bool fast) {
  if (fast) return *(volatile const int*)p;
  return __hip_atomic_load(p, __ATOMIC_RELAXED, __HIP_MEMORY_SCOPE_AGENT);
}
__device__ __forceinline__ void flag_store(int* p, int v, bool fast) {
  if (fast) *(volatile int*)p = v;
  else __hip_atomic_store(p, v, __ATOMIC_RELAXED, __HIP_MEMORY_SCOPE_AGENT);
}
__device__ __forceinline__ void x_store(unsigned* p, unsigned v, bool fast) {
  if (fast) *(volatile unsigned*)p = v;
  else __hip_atomic_store(p, v, __ATOMIC_RELAXED, __HIP_MEMORY_SCOPE_AGENT);
}

// ---------------- prep kernels ----------------

__global__ __launch_bounds__(256) void prep_wbig16(
    const float* __restrict__ W_ih, const float* __restrict__ W_hh,
    const float* __restrict__ W_lin, f16* __restrict__ Wbig16)
{
  __shared__ float As[64][20];
  __shared__ float Bs[16][68];
  const int n0 = blockIdx.x * 64;
  const int j0 = blockIdx.y * 64;
  const int tid = threadIdx.x;
  const int tn = tid >> 4, tj = tid & 15;
  float acc[4][4] = {};
  for (int k0 = 0; k0 < DD; k0 += 16) {
    { int r = tid >> 2, c = (tid & 3) * 4;
      *(float4*)&As[r][c] = *(const float4*)&W_ih[(size_t)(n0 + r) * DD + k0 + c]; }
    { int r = tid >> 4, c = (tid & 15) * 4;
      *(float4*)&Bs[r][c] = *(const float4*)&W_lin[(size_t)(k0 + r) * HH + j0 + c]; }
    __syncthreads();
    #pragma unroll
    for (int k = 0; k < 16; ++k) {
      float a[4], bv[4];
      #pragma unroll
      for (int i = 0; i < 4; ++i) a[i] = As[tn*4+i][k];
      #pragma unroll
      for (int m = 0; m < 4; ++m) bv[m] = Bs[k][tj*4+m];
      #pragma unroll
      for (int i = 0; i < 4; ++i)
        #pragma unroll
        for (int m = 0; m < 4; ++m)
          acc[i][m] = fmaf(a[i], bv[m], acc[i][m]);
    }
    __syncthreads();
  }
  #pragma unroll
  for (int i = 0; i < 4; ++i) {
    int n = n0 + tn*4 + i;
    #pragma unroll
    for (int m = 0; m < 4; ++m) {
      int j = j0 + tj*4 + m;
      Wbig16[(size_t)n*HH + j] = (f16)(acc[i][m] + W_hh[(size_t)n*HH + j]);
    }
  }
}

__global__ void prep_bias(const float* __restrict__ b_ih, const float* __restrict__ b_hh,
                          const float* __restrict__ W_ih, const float* __restrict__ b_lin,
                          float* __restrict__ bias0, float* __restrict__ bias1)
{
  int n = blockIdx.x * 256 + threadIdx.x;   // grid 8
  float s = b_ih[n] + b_hh[n];
  float d = 0.f;
  for (int k = 0; k < DD; ++k) d = fmaf(W_ih[(size_t)n*DD + k], b_lin[k], d);
  bias0[n] = s;
  bias1[n] = s + d;
}

#define NIH (G4H*DD)
#define NHH (G4H*HH)
__global__ void prep_cvtw(const float* __restrict__ W_ih, const float* __restrict__ W_hh,
                          const float* __restrict__ W_lin,
                          f16* __restrict__ Wih16, f16* __restrict__ Whh16,
                          f16* __restrict__ Wlin16)
{
  int e = blockIdx.x * 256 + threadIdx.x;   // grid 6656
  if (e < NIH) Wih16[e] = (f16)W_ih[e];
  else if (e < NIH + NHH) Whh16[e - NIH] = (f16)W_hh[e - NIH];
  else Wlin16[e - NIH - NHH] = (f16)W_lin[e - NIH - NHH];
}

__global__ void prep_init(const float* __restrict__ x0, const float* __restrict__ h0,
                          const float* __restrict__ c0,
                          const int* __restrict__ w1, const int* __restrict__ w2,
                          float* __restrict__ bh, float* __restrict__ bc,
                          f16* __restrict__ x0hi, f16* __restrict__ x0lo,
                          f16* __restrict__ h0hi, f16* __restrict__ h0lo,
                          float4* __restrict__ stepc,
                          int* __restrict__ flags)
{
  int e = blockIdx.x * 256 + threadIdx.x;   // grid 4096 -> 1048576
  int r = e & (BH - 1);
  bh[e] = h0[r];
  bc[e] = c0[r];
  if (e < BH) {
    float v = h0[e];
    f16 hi = (f16)v;
    h0hi[e] = hi;
    h0lo[e] = (f16)(v - (float)hi);
  }
  if (e < BB*DD) {
    int b = e >> 8, d = e & 255;
    float v = x0[(size_t)b*(TT*DD) + d];
    f16 hi = (f16)v;
    x0hi[e] = hi;
    x0lo[e] = (f16)(v - (float)hi);
  }
  if (e < TT) {
    float a1 = (float)w1[e], a2 = (float)w2[e];
    stepc[e] = make_float4(a1, a2, 1.f / (a1 + a2), 0.f);
  }
  if (e < 512) flags[e] = 0;   // [0..127] flags, [128..199] xcdid, [200..207] arrive
}

// ---------------- persistent main kernel ----------------

// Stage one 32 KB group-slot into linear LDS via global_load_lds.
// fast: aux=0x1 (sc0, XCD L2 coherent). slow: aux=0x11 (sc0|sc1, L3 coherent).
__device__ __forceinline__ void stageG(const unsigned* __restrict__ Xs,
                                       f16* lds, int tid, bool fast) {
  const int lane = tid & 63;
  const int wv = tid >> 6;
  #pragma unroll
  for (int i = 0; i < 4; ++i) {
    int r = wv * 4 + i;                 // row 0..31 (wave-uniform)
    const char* src = (const char*)Xs + (size_t)r * 1024 +
                      (size_t)((lane ^ (r & 31)) & 63) * 16;
    if (fast)
      __builtin_amdgcn_global_load_lds(
          (const __attribute__((address_space(1))) void*)src,
          (__attribute__((address_space(3))) void*)((char*)lds + r * 1024),
          16, 0, 0x1);
    else
      __builtin_amdgcn_global_load_lds(
          (const __attribute__((address_space(1))) void*)src,
          (__attribute__((address_space(3))) void*)((char*)lds + r * 1024),
          16, 0, 0x11);
  }
}

// K=512 single-plane MFMA GEMM from swizzled LDS, W frags in registers.
__device__ __forceinline__ f32x16 gemmS(const f16x8 (&w)[32], const f16* lds, int lane) {
  const int row = lane & 31;
  const int sel = lane >> 5;
  const int rb  = row * 1024;
  const int key = row & 31;
  f32x16 acc;
  #pragma unroll
  for (int i = 0; i < 16; ++i) acc[i] = 0.f;
  #pragma unroll
  for (int ks = 0; ks < 32; ++ks) {
    int gk = 2 * ks + sel;
    int off = rb + (((gk & 31) ^ key) << 4) + ((gk & 32) << 4);
    f16x8 a = *(const f16x8*)((const char*)lds + off);
    acc = __builtin_amdgcn_mfma_f32_32x32x16_f16(a, w[ks], acc, 0, 0, 0);
  }
  return acc;
}

// 72 blocks x 512 threads (8 waves).
// bid 0..63: gates. grp = bid&7 owns batch rows [32g,32g+32); role = bid>>3 owns
//            j-slice [64r,64r+64) x 4 gates. bid 64..71: lagging out block.
// Group sync domain chosen at runtime: if all 9 member blocks share an XCD
// (verified via HW_REG_XCC_ID rendezvous) -> L2 sc0 path, else L3 sc1 path.
__global__ __launch_bounds__(512, 2) void lstm_persist(
    const f16* __restrict__ x0hi, const f16* __restrict__ x0lo,
    const f16* __restrict__ h0hi, const f16* __restrict__ h0lo,
    const float* __restrict__ c0,
    const f16* __restrict__ Wih16, const f16* __restrict__ Whh16,
    const f16* __restrict__ Wbig16, const f16* __restrict__ Wlin16,
    const float* __restrict__ bias0, const float* __restrict__ bias1,
    const float* __restrict__ b_lin,
    const float4* __restrict__ stepc,
    unsigned* __restrict__ X,                 // 4 slots x 8 grp x XSLOT_U32
    float* __restrict__ bh, float* __restrict__ bc,
    int* __restrict__ flags,
    float* __restrict__ outp)
{
  __shared__ f16 LdsA[16384];       // 32 KB single plane
  __shared__ float gbuf[8192];      // 32 KB: [gate][32 b][64 j]

  const int tid  = threadIdx.x;
  const int lane = tid & 63;
  const int wv   = tid >> 6;            // wave 0..7
  const int bid  = blockIdx.x;
  const bool isG = bid < 64;
  const int grp  = isG ? (bid & 7) : (bid - 64);
  const int role = bid >> 3;            // gates only: 0..7
  const int b0   = grp * 32;
  const int row  = lane & 31;
  const int ksel8 = (lane >> 5) * 8;

  int* gflag  = flags + grp * 16;
  int* xcdid  = flags + 128;
  int* arrive = flags + 200;

  // ---- XCD rendezvous (one-time): publish my XCC_ID, count arrivals ----
  int xcc;
  asm volatile("s_getreg_b32 %0, hwreg(HW_REG_XCC_ID)" : "=s"(xcc));
  if (tid == 0) {
    __hip_atomic_store(&xcdid[bid], xcc, __ATOMIC_RELAXED, __HIP_MEMORY_SCOPE_AGENT);
    __hip_atomic_fetch_add(&arrive[grp], 1, __ATOMIC_RELEASE, __HIP_MEMORY_SCOPE_AGENT);
  }

  // ---- persistent W fragments (overlaps with rendezvous latency) ----
  int wrow;
  const f16* wbase;
  if (isG) {
    wrow  = (wv & 3) * 512 + role * 64 + (wv >> 2) * 32 + row;  // W_big row
    wbase = Wbig16 + (size_t)wrow * HH;
  } else {
    wrow  = wv * 32 + row;                                      // W_lin row (d-col)
    wbase = Wlin16 + (size_t)wrow * HH;
  }
  f16x8 wreg[32];
  #pragma unroll
  for (int ks = 0; ks < 32; ++ks)
    wreg[ks] = *(const f16x8*)(wbase + ks * 16 + ksel8);

  // ---- finish rendezvous, decide sync domain ----
  if (tid == 0)
    while (__hip_atomic_load(&arrive[grp], __ATOMIC_RELAXED,
                             __HIP_MEMORY_SCOPE_AGENT) < 9) {}
  __syncthreads();
  bool fast;
  {
    int id0 = __hip_atomic_load(&xcdid[grp], __ATOMIC_RELAXED, __HIP_MEMORY_SCOPE_AGENT);
    bool f = true;
    #pragma unroll
    for (int r = 1; r < 8; ++r)
      f &= (__hip_atomic_load(&xcdid[grp + 8*r], __ATOMIC_RELAXED,
                              __HIP_MEMORY_SCOPE_AGENT) == id0);
    f &= (__hip_atomic_load(&xcdid[64 + grp], __ATOMIC_RELAXED,
                            __HIP_MEMORY_SCOPE_AGENT) == id0);
    fast = f;
  }

  if (isG) {
    // ---- per-thread epilogue constants ----
    int   eidx[4];
    float creg[4];
    const int jl = tid & 63;
    const int jg = role * 64 + jl;
    const float bI = bias1[jg],        bF = bias1[512 + jg];
    const float bG = bias1[1024 + jg], bO = bias1[1536 + jg];
    #pragma unroll
    for (int i = 0; i < 4; ++i) {
      int c = i * 512 + tid;
      int bl = c >> 6;
      eidx[i] = (b0 + bl) * HH + jg;
      creg[i] = c0[eidx[i]];
    }

    for (int t = 0; t < TT; ++t) {
      if (t > 0) {
        if (tid < 8) {
          while (flag_load(&gflag[tid], fast) < t) {}
        } else if (tid == 8 && t >= 4) {
          while (flag_load(&gflag[8], fast) < t - 3) {}
        }
        __syncthreads();
        stageG(X + (size_t)(((t - 1) & 3) * 8 + grp) * XSLOT_U32, LdsA, tid, fast);
      }

      // prefetch step constants + skip reads (overlap with staging flight)
      const float4 sc = stepc[t];
      const int pos = t & (SS - 1);
      float shv[4], scv[4];
      #pragma unroll
      for (int i = 0; i < 4; ++i) {
        int bx = pos * BH + eidx[i];
        shv[i] = bh[bx];
        scv[i] = bc[bx];
      }

      f32x16 acc;
      if (t == 0) {
        #pragma unroll
        for (int i = 0; i < 16; ++i) acc[i] = 0.f;
        const f16* arh = x0hi + (size_t)(b0 + row) * DD;
        const f16* arl = x0lo + (size_t)(b0 + row) * DD;
        const f16* w1p = Wih16 + (size_t)wrow * DD;
        #pragma unroll
        for (int ks = 0; ks < 16; ++ks) {         // K=256: x0 @ W_ih^T
          int ko = ks * 16 + ksel8;
          f16x8 w = *(const f16x8*)(w1p + ko);
          acc = __builtin_amdgcn_mfma_f32_32x32x16_f16(*(const f16x8*)(arh + ko), w, acc, 0,0,0);
          acc = __builtin_amdgcn_mfma_f32_32x32x16_f16(*(const f16x8*)(arl + ko), w, acc, 0,0,0);
        }
        const f16* brh = h0hi + (size_t)(b0 + row) * HH;
        const f16* brl = h0lo + (size_t)(b0 + row) * HH;
        const f16* w2p = Whh16 + (size_t)wrow * HH;
        #pragma unroll
        for (int ks = 0; ks < 32; ++ks) {         // K=512: h0 @ W_hh^T
          int ko = ks * 16 + ksel8;
          f16x8 w = *(const f16x8*)(w2p + ko);
          acc = __builtin_amdgcn_mfma_f32_32x32x16_f16(*(const f16x8*)(brh + ko), w, acc, 0,0,0);
          acc = __builtin_amdgcn_mfma_f32_32x32x16_f16(*(const f16x8*)(brl + ko), w, acc, 0,0,0);
        }
      } else {
        __syncthreads();                 // staging complete (vmcnt drained here)
        acc = gemmS(wreg, LdsA, lane);
      }

      // acc -> gbuf [gate][b][j]
      {
        const int col = lane & 31;
        const int g4 = wv & 3, jh = wv >> 2;
        #pragma unroll
        for (int rg = 0; rg < 16; ++rg) {
          int m = (rg & 3) + ((rg >> 2) << 3) + ((lane >> 5) << 2);
          gbuf[g4 * 2048 + m * 64 + jh * 32 + col] = acc[rg];
        }
      }
      __syncthreads();

      // epilogue phase 1: gate math up to ch, publish X, flag
      const float a1 = sc.x, a2 = sc.y, nrm = sc.z;
      float baI = bI, baF = bF, baG = bG, baO = bO;
      if (t == 0) {
        baI = bias0[jg];        baF = bias0[512 + jg];
        baG = bias0[1024 + jg]; baO = bias0[1536 + jg];
      }
      unsigned* Xw = X + (size_t)((t & 3) * 8 + grp) * XSLOT_U32;
      float hnv[4], cnv[4], chv[4];
      #pragma unroll
      for (int i = 0; i < 4; ++i) {
        int c = i * 512 + tid;
        int bl = c >> 6;
        float pi = gbuf[c]        + baI;
        float pf = gbuf[2048 + c] + baF;
        float pg = gbuf[4096 + c] + baG;
        float po = gbuf[6144 + c] + baO;
        float i_ = sigm(pi), f_ = sigm(pf), o_ = sigm(po), g_ = ftanh(pg);
        float cnew = fmaf(f_, creg[i], i_ * g_);
        float hnew = o_ * ftanh(cnew);
        float ch = (a1 * hnew + a2 * ftanh(shv[i])) * nrm;
        hnv[i] = hnew; cnv[i] = cnew; chv[i] = ch;
        f16 hv = (f16)ch;
        unsigned hb = (unsigned)*(unsigned short*)&hv;
        unsigned part = (unsigned)__shfl_xor((int)hb, 1);
        if ((tid & 1) == 0)
          x_store(&Xw[bl * 256 + (jg >> 1)], hb | (part << 16), fast);
      }
      __syncthreads();                 // drains X stores of all waves (vmcnt 0)
      if (tid == 0)
        flag_store(&gflag[role], t + 1, fast);

      // epilogue phase 2 (off critical path): cc, skip buffers, finals
      #pragma unroll
      for (int i = 0; i < 4; ++i) {
        float cc = (a1 * cnv[i] + a2 * ftanh(scv[i])) * nrm;
        creg[i] = cc;
        int bx = pos * BH + eidx[i];
        bh[bx] = hnv[i];
        bc[bx] = cnv[i];
        if (t == TT - 1) {
          __builtin_nontemporal_store(chv[i], &outp[OUT_BASE + eidx[i]]);       // h_fin
          __builtin_nontemporal_store(cc,     &outp[OUT_BASE + BH + eidx[i]]);  // c_fin
        }
      }
    }
  } else {
    // ---------- lagging out-projection block (one per group) ----------
    const float bld = b_lin[wrow];
    for (int s = 0; s < TT; ++s) {
      if (tid < 8) {
        while (flag_load(&gflag[tid], fast) < s + 1) {}
      }
      __syncthreads();
      stageG(X + (size_t)((s & 3) * 8 + grp) * XSLOT_U32, LdsA, tid, fast);
      __syncthreads();                 // staging complete
      f32x16 acc = gemmS(wreg, LdsA, lane);
      __syncthreads();                 // all waves' ds_reads of the slot done
      if (tid == 0)
        flag_store(&gflag[8], s + 1, fast);
      const size_t tbase = (size_t)s * DD + wrow;
      #pragma unroll
      for (int rg = 0; rg < 16; ++rg) {
        int m = (rg & 3) + ((rg >> 2) << 3) + ((lane >> 5) << 2);
        __builtin_nontemporal_store(acc[rg] + bld,
                                    &outp[(size_t)(b0 + m) * (TT*DD) + tbase]);
      }
    }
  }
}

// ---------------- host launch ----------------

extern "C" void kernel_launch(void* const* d_in, const int* in_sizes, int n_in,
                              void* d_out, int out_size, void* d_ws, size_t ws_size,
                              hipStream_t stream)
{
  const float* x0    = (const float*)d_in[0];
  const float* h0    = (const float*)d_in[1];
  const float* c0    = (const float*)d_in[2];
  const float* W_ih  = (const float*)d_in[3];
  const float* W_hh  = (const float*)d_in[4];
  const float* b_ih  = (const float*)d_in[5];
  const float* b_hh  = (const float*)d_in[6];
  const float* W_lin = (const float*)d_in[7];
  const float* b_lin = (const float*)d_in[8];
  const int*   w1    = (const int*)d_in[9];
  const int*   w2    = (const int*)d_in[10];

  char* p = (char*)d_ws;
  f16* Wbig16 = (f16*)p;            p += (size_t)G4H*HH*2;
  f16* Wih16  = (f16*)p;            p += (size_t)G4H*DD*2;
  f16* Whh16  = (f16*)p;            p += (size_t)G4H*HH*2;
  f16* Wlin16 = (f16*)p;            p += (size_t)DD*HH*2;
  f16* x0hi   = (f16*)p;            p += (size_t)BB*DD*2;
  f16* x0lo   = (f16*)p;            p += (size_t)BB*DD*2;
  f16* h0hi   = (f16*)p;            p += (size_t)BH*2;
  f16* h0lo   = (f16*)p;            p += (size_t)BH*2;
  unsigned* X = (unsigned*)p;       p += (size_t)4*8*XSLOT_U32*4;   // 1 MB
  float* bh   = (float*)p;          p += (size_t)SS*BH*4;
  float* bc   = (float*)p;          p += (size_t)SS*BH*4;
  float* bias0= (float*)p;          p += G4H*4;
  float* bias1= (float*)p;          p += G4H*4;
  float4* stepc = (float4*)p;       p += (size_t)TT*16;
  int*  flags = (int*)p;            p += 512*4;
  float* outp = (float*)d_out;

  hipLaunchKernelGGL(prep_wbig16, dim3(32, 8), dim3(256), 0, stream,
                     W_ih, W_hh, W_lin, Wbig16);
  hipLaunchKernelGGL(prep_bias, dim3(8), dim3(256), 0, stream,
                     b_ih, b_hh, W_ih, b_lin, bias0, bias1);
  hipLaunchKernelGGL(prep_cvtw, dim3(6656), dim3(256), 0, stream,
                     W_ih, W_hh, W_lin, Wih16, Whh16, Wlin16);
  hipLaunchKernelGGL(prep_init, dim3(4096), dim3(256), 0, stream,
                     x0, h0, c0, w1, w2, bh, bc, x0hi, x0lo, h0hi, h0lo, stepc, flags);

  hipLaunchKernelGGL(lstm_persist, dim3(72), dim3(512), 0, stream,
                     x0hi, x0lo, h0hi, h0lo, c0, Wih16, Whh16, Wbig16, Wlin16,
                     bias0, bias1, b_lin, stepc, X, bh, bc, flags, outp);
}